// Round 11
// baseline (378.952 us; speedup 1.0000x reference)
//
#include <hip/hip_runtime.h>
#include <hip/hip_bf16.h>
#include <cstdint>
#include <cstddef>

static constexpr int N_NODES = 100000;
static constexpr int N_GRAPHS = 256;
static constexpr int HF = 64;

#define SCAN_T 256
#define SCAN_E 8
#define SCAN_CHUNK (SCAN_T * SCAN_E)
#define SCAN_SHIFT 11

#define BSHIFT 9
#define BNODES 512
#define ECHUNK 4096
#define SRCBITS 17

typedef unsigned short u16;
typedef unsigned int u32;
typedef unsigned long long u64;

// ---------- scan passes 1+2 (fixup folded into consumers) ----------
__global__ void scan1_k(const int* __restrict__ in, int* __restrict__ out,
                        int* __restrict__ sums, int n) {
    __shared__ int lds[SCAN_T];
    int t = threadIdx.x;
    int base = blockIdx.x * SCAN_CHUNK + t * SCAN_E;
    int v[SCAN_E];
    int s = 0;
#pragma unroll
    for (int i = 0; i < SCAN_E; ++i) {
        int idx = base + i;
        int x = (idx < n) ? in[idx] : 0;
        v[i] = s; s += x;
    }
    lds[t] = s; __syncthreads();
    for (int off = 1; off < SCAN_T; off <<= 1) {
        int a = (t >= off) ? lds[t - off] : 0;
        __syncthreads();
        lds[t] += a;
        __syncthreads();
    }
    int excl = (t == 0) ? 0 : lds[t - 1];
    if (t == SCAN_T - 1) sums[blockIdx.x] = lds[SCAN_T - 1];
#pragma unroll
    for (int i = 0; i < SCAN_E; ++i) {
        int idx = base + i;
        if (idx < n) out[idx] = excl + v[i];
    }
}

__global__ void scan2_k(int* __restrict__ sums, int nb) {
    __shared__ int lds[SCAN_T];
    int t = threadIdx.x;
    lds[t] = (t < nb) ? sums[t] : 0;
    __syncthreads();
    for (int off = 1; off < SCAN_T; off <<= 1) {
        int a = (t >= off) ? lds[t - off] : 0;
        __syncthreads();
        lds[t] += a;
        __syncthreads();
    }
    int excl = (t == 0) ? 0 : lds[t - 1];
    if (t < nb) sums[t] = excl;
}

// ---------- per-chunk bucket histogram ----------
__global__ void bhist_k(const int* __restrict__ dst, int* __restrict__ cnt,
                        int E, int nblk, int NB) {
    __shared__ int c[256];
    int t = threadIdx.x;
    c[t] = 0;
    __syncthreads();
    int base = blockIdx.x * ECHUNK;
    int m = min(ECHUNK, E - base);
    for (int i = t; i < m; i += 256) atomicAdd(&c[dst[base + i] >> BSHIFT], 1);
    __syncthreads();
    if (t < NB) cnt[t * nblk + blockIdx.x] = c[t];
}

// ---------- scatter edges into bucket partitions (scan fixup folded in) ----------
__global__ void scatter_k(const int* __restrict__ src, const int* __restrict__ dst,
                          const int* __restrict__ scn, const int* __restrict__ sums,
                          int* __restrict__ es, int E, int nblk, int NB) {
    __shared__ int offs[256];
    int t = threadIdx.x;
    if (t < NB) {
        int i = t * nblk + blockIdx.x;
        offs[t] = scn[i] + sums[i >> SCAN_SHIFT];
    }
    __syncthreads();
    int base = blockIdx.x * ECHUNK;
    int m = min(ECHUNK, E - base);
    for (int i = t; i < m; i += 256) {
        int e = base + i;
        int d = dst[e];
        int b = d >> BSHIFT;
        int p = atomicAdd(&offs[b], 1);
        es[p] = ((d & (BNODES - 1)) << SRCBITS) | src[e];
    }
}

// ---------- per-bucket: local deg, row_ptr, dinv, CSR col fill (512 thr) ----------
__global__ __launch_bounds__(512) void fill2_k(const int* __restrict__ es,
                                               const int* __restrict__ scn,
                                               const int* __restrict__ sums,
                                               int* __restrict__ rowp, int* __restrict__ deg,
                                               float* __restrict__ dinv, int* __restrict__ col,
                                               int E, int nblk, int NB, int N) {
    __shared__ int ldeg[BNODES];
    __shared__ int rp[BNODES];
    __shared__ int tmp[BNODES];
    int b = blockIdx.x, t = threadIdx.x;
    int i0 = b * nblk;
    int ebase = scn[i0] + sums[i0 >> SCAN_SHIFT];
    int eend;
    if (b + 1 < NB) {
        int i1 = (b + 1) * nblk;
        eend = scn[i1] + sums[i1 >> SCAN_SHIFT];
    } else {
        eend = E;
    }
    int d0 = b << BSHIFT;
    int nd = min(BNODES, N - d0);
    ldeg[t] = 0;
    __syncthreads();
    for (int e = ebase + t; e < eend; e += 512) atomicAdd(&ldeg[((u32)es[e]) >> SRCBITS], 1);
    __syncthreads();
    int a = ldeg[t];
    tmp[t] = a;
    __syncthreads();
    for (int off = 1; off < BNODES; off <<= 1) {
        int v = (t >= off) ? tmp[t - off] : 0;
        __syncthreads();
        tmp[t] += v;
        __syncthreads();
    }
    rp[t] = tmp[t] - a;   // exclusive
    __syncthreads();
    if (t < nd) {
        int d = d0 + t;
        rowp[d] = ebase + rp[t];
        deg[d] = a;
        dinv[d] = rsqrtf((float)(a + 1));
    }
    ldeg[t] = 0;  // reuse as position counters
    __syncthreads();
    for (int e = ebase + t; e < eend; e += 512) {
        u32 w = (u32)es[e];
        int li = w >> SRCBITS;
        int p = atomicAdd(&ldeg[li], 1);
        col[ebase + rp[li] + p] = (int)(w & ((1u << SRCBITS) - 1));
    }
}

// ---------- merged W transposes: W4[k4*64+c] = {W[4k4..4k4+3][c]} for W1,W2,W3 ----------
__global__ void wtrans3_k(const float* __restrict__ W1, float4* __restrict__ W4_1,
                          const float* __restrict__ W2, float4* __restrict__ W4_2,
                          const float* __restrict__ W3, float4* __restrict__ W4_3) {
    int idx = blockIdx.x * blockDim.x + threadIdx.x;  // 0..4095
    const float* W;
    float4* W4;
    int li;
    if (idx < 2048)      { W = W1; W4 = W4_1; li = idx; }
    else if (idx < 3072) { W = W2; W4 = W4_2; li = idx - 2048; }
    else                 { W = W3; W4 = W4_3; li = idx - 3072; }
    int k4 = li >> 6, c = li & 63;
    W4[li] = make_float4(W[(4 * k4 + 0) * HF + c], W[(4 * k4 + 1) * HF + c],
                         W[(4 * k4 + 2) * HF + c], W[(4 * k4 + 3) * HF + c]);
}

#define DOT4(A, B, ACC) \
    ACC = fmaf((A).x, (B).x, fmaf((A).y, (B).y, fmaf((A).z, (B).z, fmaf((A).w, (B).w, (ACC)))))

// ---------- u = bf16((in @ W) * dinv[row])  (register-tiled 4x4, LDS, no broadcasts) ----------
template <int K>
__global__ __launch_bounds__(256, 4) void gemm6_k(const float* __restrict__ in,
                                                  const float4* __restrict__ W4,
                                                  const float* __restrict__ dinv,
                                                  __hip_bfloat16* __restrict__ u, int n) {
    __shared__ float4 Wl[16 * HF];   // [k4][col] chunk, 16 KB
    __shared__ float4 Xl[64 * 17];   // [row][k4 + pad], 17.4 KB
    int t = threadIdx.x;
    int wave = t >> 6, lane = t & 63;
    int mi = lane >> 3, ni = lane & 7;
    int qr = (wave >> 1) * 32, qc = (wave & 1) * 32;
    int rb = blockIdx.x * 64;
    float acc[4][4];
#pragma unroll
    for (int i = 0; i < 4; ++i)
#pragma unroll
        for (int j = 0; j < 4; ++j) acc[i][j] = 0.f;
    constexpr int NC = K / 64;
#pragma unroll 1
    for (int kc = 0; kc < NC; ++kc) {
        const float4* Wc = W4 + kc * 16 * HF;
#pragma unroll 1
        for (int i = t; i < 16 * HF; i += 256) Wl[i] = Wc[i];
        {
            int r = t >> 4, q = t & 15;
#pragma unroll 1
            for (int i = 0; i < 4; ++i) {
                int row = r + i * 16;
                int gr = rb + row;
                float4 v = (gr < n)
                    ? *(const float4*)(in + (size_t)gr * K + kc * 64 + q * 4)
                    : make_float4(0.f, 0.f, 0.f, 0.f);
                Xl[row * 17 + q] = v;
            }
        }
        __syncthreads();
#pragma unroll 1
        for (int k4 = 0; k4 < 16; ++k4) {
            float4 a0 = Xl[(qr + mi + 0) * 17 + k4];
            float4 a1 = Xl[(qr + mi + 8) * 17 + k4];
            float4 a2 = Xl[(qr + mi + 16) * 17 + k4];
            float4 a3 = Xl[(qr + mi + 24) * 17 + k4];
            float4 b0 = Wl[k4 * HF + qc + ni + 0];
            float4 b1 = Wl[k4 * HF + qc + ni + 8];
            float4 b2 = Wl[k4 * HF + qc + ni + 16];
            float4 b3 = Wl[k4 * HF + qc + ni + 24];
            DOT4(a0, b0, acc[0][0]); DOT4(a0, b1, acc[0][1]);
            DOT4(a0, b2, acc[0][2]); DOT4(a0, b3, acc[0][3]);
            DOT4(a1, b0, acc[1][0]); DOT4(a1, b1, acc[1][1]);
            DOT4(a1, b2, acc[1][2]); DOT4(a1, b3, acc[1][3]);
            DOT4(a2, b0, acc[2][0]); DOT4(a2, b1, acc[2][1]);
            DOT4(a2, b2, acc[2][2]); DOT4(a2, b3, acc[2][3]);
            DOT4(a3, b0, acc[3][0]); DOT4(a3, b1, acc[3][1]);
            DOT4(a3, b2, acc[3][2]); DOT4(a3, b3, acc[3][3]);
        }
        __syncthreads();
    }
#pragma unroll
    for (int i = 0; i < 4; ++i) {
        int row = rb + qr + mi + 8 * i;
        if (row < n) {
            float dv = dinv[row];
#pragma unroll
            for (int j = 0; j < 4; ++j) {
                u[(size_t)row * HF + qc + ni + 8 * j] = __float2bfloat16(acc[i][j] * dv);
            }
        }
    }
}

#define UNPACK_ADD(Q)                                                       \
    do {                                                                    \
        a0 += __uint_as_float((Q).x << 16); a1 += __uint_as_float((Q).x & 0xffff0000u); \
        a2 += __uint_as_float((Q).y << 16); a3 += __uint_as_float((Q).y & 0xffff0000u); \
        a4 += __uint_as_float((Q).z << 16); a5 += __uint_as_float((Q).z & 0xffff0000u); \
        a6 += __uint_as_float((Q).w << 16); a7 += __uint_as_float((Q).w & 0xffff0000u); \
    } while (0)

// ---------- aggregation (bf16 gather): out[v] = relu(dinv[v]*(sum u[s] + u[v]) + b) ----------
// Eighth-wave (8 lanes) per node: lane loads uint4 (16B = 8 bf16 feats) -> 8x16 =
// 128B row per instr; 8 independent node streams/wave x 8-deep = 64 loads in flight.
// Neighbor summation order identical to agg3 -> bit-identical output.
__global__ __launch_bounds__(256) void agg4_k(const uint4* __restrict__ u,
                                              const int* __restrict__ col,
                                              const int* __restrict__ rowp,
                                              const int* __restrict__ deg,
                                              const float* __restrict__ dinv,
                                              const float* __restrict__ bias,
                                              float* __restrict__ out, int n) {
    int t = threadIdx.x;
    int el = t & 7;
    int v = blockIdx.x * 32 + (t >> 3);
    if (v >= n) return;
    uint4 q = u[(size_t)v * 8 + el];  // self loop
    float a0 = __uint_as_float(q.x << 16), a1 = __uint_as_float(q.x & 0xffff0000u);
    float a2 = __uint_as_float(q.y << 16), a3 = __uint_as_float(q.y & 0xffff0000u);
    float a4 = __uint_as_float(q.z << 16), a5 = __uint_as_float(q.z & 0xffff0000u);
    float a6 = __uint_as_float(q.w << 16), a7 = __uint_as_float(q.w & 0xffff0000u);
    int start = rowp[v];
    int nE = deg[v];
    for (int e = 0; e < nE;) {
        int m = min(8, nE - e);
        int c = (el < m) ? col[start + e + el] : 0;
        if (m == 8) {
            int s0 = __shfl(c, 0, 8), s1 = __shfl(c, 1, 8);
            int s2 = __shfl(c, 2, 8), s3 = __shfl(c, 3, 8);
            int s4 = __shfl(c, 4, 8), s5 = __shfl(c, 5, 8);
            int s6 = __shfl(c, 6, 8), s7 = __shfl(c, 7, 8);
            uint4 q0 = u[(size_t)s0 * 8 + el];
            uint4 q1 = u[(size_t)s1 * 8 + el];
            uint4 q2 = u[(size_t)s2 * 8 + el];
            uint4 q3 = u[(size_t)s3 * 8 + el];
            uint4 q4 = u[(size_t)s4 * 8 + el];
            uint4 q5 = u[(size_t)s5 * 8 + el];
            uint4 q6 = u[(size_t)s6 * 8 + el];
            uint4 q7 = u[(size_t)s7 * 8 + el];
            UNPACK_ADD(q0); UNPACK_ADD(q1); UNPACK_ADD(q2); UNPACK_ADD(q3);
            UNPACK_ADD(q4); UNPACK_ADD(q5); UNPACK_ADD(q6); UNPACK_ADD(q7);
        } else {
            for (int i = 0; i < m; ++i) {
                int s = __shfl(c, i, 8);
                uint4 qq = u[(size_t)s * 8 + el];
                UNPACK_ADD(qq);
            }
        }
        e += m;
    }
    float dv = dinv[v];
    float4 b0 = ((const float4*)bias)[2 * el];
    float4 b1 = ((const float4*)bias)[2 * el + 1];
    float4 o0, o1;
    o0.x = fmaxf(fmaf(a0, dv, b0.x), 0.f);
    o0.y = fmaxf(fmaf(a1, dv, b0.y), 0.f);
    o0.z = fmaxf(fmaf(a2, dv, b0.z), 0.f);
    o0.w = fmaxf(fmaf(a3, dv, b0.w), 0.f);
    o1.x = fmaxf(fmaf(a4, dv, b1.x), 0.f);
    o1.y = fmaxf(fmaf(a5, dv, b1.y), 0.f);
    o1.z = fmaxf(fmaf(a6, dv, b1.z), 0.f);
    o1.w = fmaxf(fmaf(a7, dv, b1.w), 0.f);
    ((float4*)out)[(size_t)v * 16 + 2 * el] = o0;
    ((float4*)out)[(size_t)v * 16 + 2 * el + 1] = o1;
}

// ---------- fused mean-pool + linear head ----------
__device__ __forceinline__ int lower_bound_i(const int* a, int n, int key) {
    int lo = 0, hi = n;
    while (lo < hi) { int mid = (lo + hi) >> 1; if (a[mid] < key) lo = mid + 1; else hi = mid; }
    return lo;
}

__global__ void pool_head_k(const float* __restrict__ h, const int* __restrict__ batch,
                            const float* __restrict__ Wl, const float* __restrict__ bl,
                            float* __restrict__ out, int n) {
    __shared__ float ssum[4][HF];
    __shared__ float smean[HF];
    int g = blockIdx.x;
    int wave = threadIdx.x >> 6, lane = threadIdx.x & 63;
    int start = lower_bound_i(batch, n, g);
    int end = lower_bound_i(batch, n, g + 1);
    float acc = 0.f;
    for (int v = start + wave; v < end; v += 4) acc += h[(size_t)v * HF + lane];
    ssum[wave][lane] = acc;
    __syncthreads();
    if (wave == 0) {
        float s = ssum[0][lane] + ssum[1][lane] + ssum[2][lane] + ssum[3][lane];
        float cnt = (float)(end - start);
        smean[lane] = s / fmaxf(cnt, 1.f);
    }
    __syncthreads();
    if (threadIdx.x < 2) {
        float o = bl[threadIdx.x];
        for (int j = 0; j < HF; ++j) o += smean[j] * Wl[j * 2 + threadIdx.x];
        out[g * 2 + threadIdx.x] = o;
    }
}

extern "C" void kernel_launch(void* const* d_in, const int* in_sizes, int n_in,
                              void* d_out, int out_size, void* d_ws, size_t ws_size,
                              hipStream_t stream) {
    const float* x     = (const float*)d_in[0];
    const int*   ei    = (const int*)d_in[1];
    const int*   batch = (const int*)d_in[2];
    const float* W1 = (const float*)d_in[3];
    const float* b1 = (const float*)d_in[4];
    const float* W2 = (const float*)d_in[5];
    const float* b2 = (const float*)d_in[6];
    const float* W3 = (const float*)d_in[7];
    const float* b3 = (const float*)d_in[8];
    const float* Wl = (const float*)d_in[9];
    const float* bl = (const float*)d_in[10];
    float* outp = (float*)d_out;

    const int N = N_NODES;
    const int E = in_sizes[1] / 2;
    const int NB = (N + BNODES - 1) >> BSHIFT;        // 196 buckets
    const int NBLK = (E + ECHUNK - 1) / ECHUNK;       // edge chunks (~782)
    const int M = NB * NBLK;                          // (bucket, chunk) counts

    char* ws = (char*)d_ws;
    size_t off = 0;
    auto alloc = [&](size_t bytes) {
        void* p = ws + off;
        off = (off + bytes + 255) & ~size_t(255);
        return p;
    };
    size_t ubytes = (size_t)N * HF * 2;
    if ((size_t)E * 4 > ubytes) ubytes = (size_t)E * 4;
    float*  P    = (float*)alloc((size_t)N * HF * 4);
    void*   Uv   = alloc(ubytes);                     // bf16 u; also sorted edges pre-gemm
    int*    colA = (int*)alloc((size_t)E * 4);
    int*    deg  = (int*)alloc((size_t)N * 4);
    float*  dinv = (float*)alloc((size_t)N * 4);
    int*    rowp = (int*)alloc((size_t)N * 4);
    int*    cnt  = (int*)alloc((size_t)M * 4);
    int*    scn  = (int*)alloc((size_t)M * 4);
    int*    sums = (int*)alloc(4096);
    float4* W4_1 = (float4*)alloc((size_t)(128 / 4) * HF * 16);
    float4* W4_2 = (float4*)alloc((size_t)(64 / 4) * HF * 16);
    float4* W4_3 = (float4*)alloc((size_t)(64 / 4) * HF * 16);
    __hip_bfloat16* U = (__hip_bfloat16*)Uv;
    uint4* U4 = (uint4*)Uv;
    int* es  = (int*)Uv;
    (void)ws_size; (void)n_in; (void)out_size;

    const int* src = ei;
    const int* dst = ei + E;

    // ---- build bucket-sorted edge list + CSR (scan3 folded into consumers) ----
    bhist_k<<<NBLK, 256, 0, stream>>>(dst, cnt, E, NBLK, NB);
    int nb = (M + SCAN_CHUNK - 1) / SCAN_CHUNK;
    scan1_k<<<nb, SCAN_T, 0, stream>>>(cnt, scn, sums, M);
    scan2_k<<<1, SCAN_T, 0, stream>>>(sums, nb);
    scatter_k<<<NBLK, 256, 0, stream>>>(src, dst, scn, sums, es, E, NBLK, NB);
    fill2_k<<<NB, 512, 0, stream>>>(es, scn, sums, rowp, deg, dinv, colA, E, NBLK, NB, N);

    // one-time W transforms (single launch)
    wtrans3_k<<<16, 256, 0, stream>>>(W1, W4_1, W2, W4_2, W3, W4_3);

    int gRow32 = (N + 31) / 32;   // agg: 32 nodes/block (eighth-wave per node)
    int gRow64 = (N + 63) / 64;   // gemm: 64 rows/block
    // layer 1 (K=128)
    gemm6_k<128><<<gRow64, 256, 0, stream>>>(x, W4_1, dinv, U, N);
    agg4_k<<<gRow32, 256, 0, stream>>>(U4, colA, rowp, deg, dinv, b1, P, N);
    // layer 2 (K=64)
    gemm6_k<64><<<gRow64, 256, 0, stream>>>(P, W4_2, dinv, U, N);
    agg4_k<<<gRow32, 256, 0, stream>>>(U4, colA, rowp, deg, dinv, b2, P, N);
    // layer 3 (K=64)
    gemm6_k<64><<<gRow64, 256, 0, stream>>>(P, W4_3, dinv, U, N);
    agg4_k<<<gRow32, 256, 0, stream>>>(U4, colA, rowp, deg, dinv, b3, P, N);

    pool_head_k<<<N_GRAPHS, 256, 0, stream>>>(P, batch, Wl, bl, outp, N);
}

// Round 12
// 344.725 us; speedup vs baseline: 1.0993x; 1.0993x over previous
//
#include <hip/hip_runtime.h>
#include <hip/hip_bf16.h>
#include <cstdint>
#include <cstddef>

static constexpr int N_NODES = 100000;
static constexpr int N_GRAPHS = 256;
static constexpr int HF = 64;

#define SCAN_T 256
#define SCAN_E 8
#define SCAN_CHUNK (SCAN_T * SCAN_E)
#define SCAN_SHIFT 11

#define BSHIFT 9
#define BNODES 512
#define ECHUNK 4096
#define SRCBITS 17

typedef unsigned short u16;
typedef unsigned int u32;
typedef unsigned long long u64;

// ---------- scan passes 1+2 (fixup folded into consumers) ----------
__global__ void scan1_k(const int* __restrict__ in, int* __restrict__ out,
                        int* __restrict__ sums, int n) {
    __shared__ int lds[SCAN_T];
    int t = threadIdx.x;
    int base = blockIdx.x * SCAN_CHUNK + t * SCAN_E;
    int v[SCAN_E];
    int s = 0;
#pragma unroll
    for (int i = 0; i < SCAN_E; ++i) {
        int idx = base + i;
        int x = (idx < n) ? in[idx] : 0;
        v[i] = s; s += x;
    }
    lds[t] = s; __syncthreads();
    for (int off = 1; off < SCAN_T; off <<= 1) {
        int a = (t >= off) ? lds[t - off] : 0;
        __syncthreads();
        lds[t] += a;
        __syncthreads();
    }
    int excl = (t == 0) ? 0 : lds[t - 1];
    if (t == SCAN_T - 1) sums[blockIdx.x] = lds[SCAN_T - 1];
#pragma unroll
    for (int i = 0; i < SCAN_E; ++i) {
        int idx = base + i;
        if (idx < n) out[idx] = excl + v[i];
    }
}

__global__ void scan2_k(int* __restrict__ sums, int nb) {
    __shared__ int lds[SCAN_T];
    int t = threadIdx.x;
    lds[t] = (t < nb) ? sums[t] : 0;
    __syncthreads();
    for (int off = 1; off < SCAN_T; off <<= 1) {
        int a = (t >= off) ? lds[t - off] : 0;
        __syncthreads();
        lds[t] += a;
        __syncthreads();
    }
    int excl = (t == 0) ? 0 : lds[t - 1];
    if (t < nb) sums[t] = excl;
}

// ---------- per-chunk bucket histogram ----------
__global__ void bhist_k(const int* __restrict__ dst, int* __restrict__ cnt,
                        int E, int nblk, int NB) {
    __shared__ int c[256];
    int t = threadIdx.x;
    c[t] = 0;
    __syncthreads();
    int base = blockIdx.x * ECHUNK;
    int m = min(ECHUNK, E - base);
    for (int i = t; i < m; i += 256) atomicAdd(&c[dst[base + i] >> BSHIFT], 1);
    __syncthreads();
    if (t < NB) cnt[t * nblk + blockIdx.x] = c[t];
}

// ---------- scatter edges into bucket partitions (scan fixup folded in) ----------
__global__ void scatter_k(const int* __restrict__ src, const int* __restrict__ dst,
                          const int* __restrict__ scn, const int* __restrict__ sums,
                          int* __restrict__ es, int E, int nblk, int NB) {
    __shared__ int offs[256];
    int t = threadIdx.x;
    if (t < NB) {
        int i = t * nblk + blockIdx.x;
        offs[t] = scn[i] + sums[i >> SCAN_SHIFT];
    }
    __syncthreads();
    int base = blockIdx.x * ECHUNK;
    int m = min(ECHUNK, E - base);
    for (int i = t; i < m; i += 256) {
        int e = base + i;
        int d = dst[e];
        int b = d >> BSHIFT;
        int p = atomicAdd(&offs[b], 1);
        es[p] = ((d & (BNODES - 1)) << SRCBITS) | src[e];
    }
}

// ---------- per-bucket: local deg, row_ptr, dinv, CSR col fill (512 thr) ----------
__global__ __launch_bounds__(512) void fill2_k(const int* __restrict__ es,
                                               const int* __restrict__ scn,
                                               const int* __restrict__ sums,
                                               int* __restrict__ rowp, int* __restrict__ deg,
                                               float* __restrict__ dinv, int* __restrict__ col,
                                               int E, int nblk, int NB, int N) {
    __shared__ int ldeg[BNODES];
    __shared__ int rp[BNODES];
    __shared__ int tmp[BNODES];
    int b = blockIdx.x, t = threadIdx.x;
    int i0 = b * nblk;
    int ebase = scn[i0] + sums[i0 >> SCAN_SHIFT];
    int eend;
    if (b + 1 < NB) {
        int i1 = (b + 1) * nblk;
        eend = scn[i1] + sums[i1 >> SCAN_SHIFT];
    } else {
        eend = E;
    }
    int d0 = b << BSHIFT;
    int nd = min(BNODES, N - d0);
    ldeg[t] = 0;
    __syncthreads();
    for (int e = ebase + t; e < eend; e += 512) atomicAdd(&ldeg[((u32)es[e]) >> SRCBITS], 1);
    __syncthreads();
    int a = ldeg[t];
    tmp[t] = a;
    __syncthreads();
    for (int off = 1; off < BNODES; off <<= 1) {
        int v = (t >= off) ? tmp[t - off] : 0;
        __syncthreads();
        tmp[t] += v;
        __syncthreads();
    }
    rp[t] = tmp[t] - a;   // exclusive
    __syncthreads();
    if (t < nd) {
        int d = d0 + t;
        rowp[d] = ebase + rp[t];
        deg[d] = a;
        dinv[d] = rsqrtf((float)(a + 1));
    }
    ldeg[t] = 0;  // reuse as position counters
    __syncthreads();
    for (int e = ebase + t; e < eend; e += 512) {
        u32 w = (u32)es[e];
        int li = w >> SRCBITS;
        int p = atomicAdd(&ldeg[li], 1);
        col[ebase + rp[li] + p] = (int)(w & ((1u << SRCBITS) - 1));
    }
}

// ---------- merged W transposes: W4[k4*64+c] = {W[4k4..4k4+3][c]} for W1,W2,W3 ----------
__global__ void wtrans3_k(const float* __restrict__ W1, float4* __restrict__ W4_1,
                          const float* __restrict__ W2, float4* __restrict__ W4_2,
                          const float* __restrict__ W3, float4* __restrict__ W4_3) {
    int idx = blockIdx.x * blockDim.x + threadIdx.x;  // 0..4095
    const float* W;
    float4* W4;
    int li;
    if (idx < 2048)      { W = W1; W4 = W4_1; li = idx; }
    else if (idx < 3072) { W = W2; W4 = W4_2; li = idx - 2048; }
    else                 { W = W3; W4 = W4_3; li = idx - 3072; }
    int k4 = li >> 6, c = li & 63;
    W4[li] = make_float4(W[(4 * k4 + 0) * HF + c], W[(4 * k4 + 1) * HF + c],
                         W[(4 * k4 + 2) * HF + c], W[(4 * k4 + 3) * HF + c]);
}

#define DOT4(A, B, ACC) \
    ACC = fmaf((A).x, (B).x, fmaf((A).y, (B).y, fmaf((A).z, (B).z, fmaf((A).w, (B).w, (ACC)))))

// ---------- u = bf16((in @ W) * dinv[row])  (register-tiled 4x4, LDS, no broadcasts) ----------
template <int K>
__global__ __launch_bounds__(256, 4) void gemm6_k(const float* __restrict__ in,
                                                  const float4* __restrict__ W4,
                                                  const float* __restrict__ dinv,
                                                  __hip_bfloat16* __restrict__ u, int n) {
    __shared__ float4 Wl[16 * HF];   // [k4][col] chunk, 16 KB
    __shared__ float4 Xl[64 * 17];   // [row][k4 + pad], 17.4 KB
    int t = threadIdx.x;
    int wave = t >> 6, lane = t & 63;
    int mi = lane >> 3, ni = lane & 7;
    int qr = (wave >> 1) * 32, qc = (wave & 1) * 32;
    int rb = blockIdx.x * 64;
    float acc[4][4];
#pragma unroll
    for (int i = 0; i < 4; ++i)
#pragma unroll
        for (int j = 0; j < 4; ++j) acc[i][j] = 0.f;
    constexpr int NC = K / 64;
#pragma unroll 1
    for (int kc = 0; kc < NC; ++kc) {
        const float4* Wc = W4 + kc * 16 * HF;
#pragma unroll 1
        for (int i = t; i < 16 * HF; i += 256) Wl[i] = Wc[i];
        {
            int r = t >> 4, q = t & 15;
#pragma unroll 1
            for (int i = 0; i < 4; ++i) {
                int row = r + i * 16;
                int gr = rb + row;
                float4 v = (gr < n)
                    ? *(const float4*)(in + (size_t)gr * K + kc * 64 + q * 4)
                    : make_float4(0.f, 0.f, 0.f, 0.f);
                Xl[row * 17 + q] = v;
            }
        }
        __syncthreads();
#pragma unroll 1
        for (int k4 = 0; k4 < 16; ++k4) {
            float4 a0 = Xl[(qr + mi + 0) * 17 + k4];
            float4 a1 = Xl[(qr + mi + 8) * 17 + k4];
            float4 a2 = Xl[(qr + mi + 16) * 17 + k4];
            float4 a3 = Xl[(qr + mi + 24) * 17 + k4];
            float4 b0 = Wl[k4 * HF + qc + ni + 0];
            float4 b1 = Wl[k4 * HF + qc + ni + 8];
            float4 b2 = Wl[k4 * HF + qc + ni + 16];
            float4 b3 = Wl[k4 * HF + qc + ni + 24];
            DOT4(a0, b0, acc[0][0]); DOT4(a0, b1, acc[0][1]);
            DOT4(a0, b2, acc[0][2]); DOT4(a0, b3, acc[0][3]);
            DOT4(a1, b0, acc[1][0]); DOT4(a1, b1, acc[1][1]);
            DOT4(a1, b2, acc[1][2]); DOT4(a1, b3, acc[1][3]);
            DOT4(a2, b0, acc[2][0]); DOT4(a2, b1, acc[2][1]);
            DOT4(a2, b2, acc[2][2]); DOT4(a2, b3, acc[2][3]);
            DOT4(a3, b0, acc[3][0]); DOT4(a3, b1, acc[3][1]);
            DOT4(a3, b2, acc[3][2]); DOT4(a3, b3, acc[3][3]);
        }
        __syncthreads();
    }
#pragma unroll
    for (int i = 0; i < 4; ++i) {
        int row = rb + qr + mi + 8 * i;
        if (row < n) {
            float dv = dinv[row];
#pragma unroll
            for (int j = 0; j < 4; ++j) {
                u[(size_t)row * HF + qc + ni + 8 * j] = __float2bfloat16(acc[i][j] * dv);
            }
        }
    }
}

// ---------- aggregation (bf16 gather): out[v] = relu(dinv[v]*(sum u[s] + u[v]) + b) ----------
// PROVEN R9/R10 config: quarter-wave (16 lanes) per node, u64 (8B) loads ->
// 128B/row per instr, 4 node streams/wave, 8-deep unroll. Local optimum:
// 8-lane/uint4 variant (R11) regressed via VGPR/occupancy. Do not revisit.
__global__ __launch_bounds__(256) void agg3_k(const u64* __restrict__ u,
                                              const int* __restrict__ col,
                                              const int* __restrict__ rowp,
                                              const int* __restrict__ deg,
                                              const float* __restrict__ dinv,
                                              const float* __restrict__ bias,
                                              float* __restrict__ out, int n) {
    int t = threadIdx.x;
    int ql = t & 15;
    int v = blockIdx.x * 16 + (t >> 4);
    if (v >= n) return;
    u64 q = u[(size_t)v * 16 + ql];  // self loop
    u32 lo = (u32)q, hi = (u32)(q >> 32);
    float a0 = __uint_as_float(lo << 16);
    float a1 = __uint_as_float(lo & 0xffff0000u);
    float a2 = __uint_as_float(hi << 16);
    float a3 = __uint_as_float(hi & 0xffff0000u);
    int start = rowp[v];
    int nE = deg[v];
    for (int e = 0; e < nE;) {
        int m = min(16, nE - e);
        int c = (ql < m) ? col[start + e + ql] : 0;
        int i = 0;
        for (; i + 8 <= m; i += 8) {
            int s0 = __shfl(c, i, 16),     s1 = __shfl(c, i + 1, 16);
            int s2 = __shfl(c, i + 2, 16), s3 = __shfl(c, i + 3, 16);
            int s4 = __shfl(c, i + 4, 16), s5 = __shfl(c, i + 5, 16);
            int s6 = __shfl(c, i + 6, 16), s7 = __shfl(c, i + 7, 16);
            u64 q0 = u[(size_t)s0 * 16 + ql];
            u64 q1 = u[(size_t)s1 * 16 + ql];
            u64 q2 = u[(size_t)s2 * 16 + ql];
            u64 q3 = u[(size_t)s3 * 16 + ql];
            u64 q4 = u[(size_t)s4 * 16 + ql];
            u64 q5 = u[(size_t)s5 * 16 + ql];
            u64 q6 = u[(size_t)s6 * 16 + ql];
            u64 q7 = u[(size_t)s7 * 16 + ql];
            u32 l, h;
            l = (u32)q0; h = (u32)(q0 >> 32);
            a0 += __uint_as_float(l << 16); a1 += __uint_as_float(l & 0xffff0000u);
            a2 += __uint_as_float(h << 16); a3 += __uint_as_float(h & 0xffff0000u);
            l = (u32)q1; h = (u32)(q1 >> 32);
            a0 += __uint_as_float(l << 16); a1 += __uint_as_float(l & 0xffff0000u);
            a2 += __uint_as_float(h << 16); a3 += __uint_as_float(h & 0xffff0000u);
            l = (u32)q2; h = (u32)(q2 >> 32);
            a0 += __uint_as_float(l << 16); a1 += __uint_as_float(l & 0xffff0000u);
            a2 += __uint_as_float(h << 16); a3 += __uint_as_float(h & 0xffff0000u);
            l = (u32)q3; h = (u32)(q3 >> 32);
            a0 += __uint_as_float(l << 16); a1 += __uint_as_float(l & 0xffff0000u);
            a2 += __uint_as_float(h << 16); a3 += __uint_as_float(h & 0xffff0000u);
            l = (u32)q4; h = (u32)(q4 >> 32);
            a0 += __uint_as_float(l << 16); a1 += __uint_as_float(l & 0xffff0000u);
            a2 += __uint_as_float(h << 16); a3 += __uint_as_float(h & 0xffff0000u);
            l = (u32)q5; h = (u32)(q5 >> 32);
            a0 += __uint_as_float(l << 16); a1 += __uint_as_float(l & 0xffff0000u);
            a2 += __uint_as_float(h << 16); a3 += __uint_as_float(h & 0xffff0000u);
            l = (u32)q6; h = (u32)(q6 >> 32);
            a0 += __uint_as_float(l << 16); a1 += __uint_as_float(l & 0xffff0000u);
            a2 += __uint_as_float(h << 16); a3 += __uint_as_float(h & 0xffff0000u);
            l = (u32)q7; h = (u32)(q7 >> 32);
            a0 += __uint_as_float(l << 16); a1 += __uint_as_float(l & 0xffff0000u);
            a2 += __uint_as_float(h << 16); a3 += __uint_as_float(h & 0xffff0000u);
        }
        for (; i < m; ++i) {
            int s = __shfl(c, i, 16);
            u64 qq = u[(size_t)s * 16 + ql];
            u32 l = (u32)qq, h = (u32)(qq >> 32);
            a0 += __uint_as_float(l << 16);
            a1 += __uint_as_float(l & 0xffff0000u);
            a2 += __uint_as_float(h << 16);
            a3 += __uint_as_float(h & 0xffff0000u);
        }
        e += m;
    }
    float dv = dinv[v];
    float4 bb = ((const float4*)bias)[ql];
    float4 o;
    o.x = fmaxf(fmaf(a0, dv, bb.x), 0.f);
    o.y = fmaxf(fmaf(a1, dv, bb.y), 0.f);
    o.z = fmaxf(fmaf(a2, dv, bb.z), 0.f);
    o.w = fmaxf(fmaf(a3, dv, bb.w), 0.f);
    ((float4*)out)[(size_t)v * 16 + ql] = o;
}

// ---------- fused mean-pool + linear head ----------
__device__ __forceinline__ int lower_bound_i(const int* a, int n, int key) {
    int lo = 0, hi = n;
    while (lo < hi) { int mid = (lo + hi) >> 1; if (a[mid] < key) lo = mid + 1; else hi = mid; }
    return lo;
}

__global__ void pool_head_k(const float* __restrict__ h, const int* __restrict__ batch,
                            const float* __restrict__ Wl, const float* __restrict__ bl,
                            float* __restrict__ out, int n) {
    __shared__ float ssum[4][HF];
    __shared__ float smean[HF];
    int g = blockIdx.x;
    int wave = threadIdx.x >> 6, lane = threadIdx.x & 63;
    int start = lower_bound_i(batch, n, g);
    int end = lower_bound_i(batch, n, g + 1);
    float acc = 0.f;
    for (int v = start + wave; v < end; v += 4) acc += h[(size_t)v * HF + lane];
    ssum[wave][lane] = acc;
    __syncthreads();
    if (wave == 0) {
        float s = ssum[0][lane] + ssum[1][lane] + ssum[2][lane] + ssum[3][lane];
        float cnt = (float)(end - start);
        smean[lane] = s / fmaxf(cnt, 1.f);
    }
    __syncthreads();
    if (threadIdx.x < 2) {
        float o = bl[threadIdx.x];
        for (int j = 0; j < HF; ++j) o += smean[j] * Wl[j * 2 + threadIdx.x];
        out[g * 2 + threadIdx.x] = o;
    }
}

extern "C" void kernel_launch(void* const* d_in, const int* in_sizes, int n_in,
                              void* d_out, int out_size, void* d_ws, size_t ws_size,
                              hipStream_t stream) {
    const float* x     = (const float*)d_in[0];
    const int*   ei    = (const int*)d_in[1];
    const int*   batch = (const int*)d_in[2];
    const float* W1 = (const float*)d_in[3];
    const float* b1 = (const float*)d_in[4];
    const float* W2 = (const float*)d_in[5];
    const float* b2 = (const float*)d_in[6];
    const float* W3 = (const float*)d_in[7];
    const float* b3 = (const float*)d_in[8];
    const float* Wl = (const float*)d_in[9];
    const float* bl = (const float*)d_in[10];
    float* outp = (float*)d_out;

    const int N = N_NODES;
    const int E = in_sizes[1] / 2;
    const int NB = (N + BNODES - 1) >> BSHIFT;        // 196 buckets
    const int NBLK = (E + ECHUNK - 1) / ECHUNK;       // edge chunks (~782)
    const int M = NB * NBLK;                          // (bucket, chunk) counts

    char* ws = (char*)d_ws;
    size_t off = 0;
    auto alloc = [&](size_t bytes) {
        void* p = ws + off;
        off = (off + bytes + 255) & ~size_t(255);
        return p;
    };
    size_t ubytes = (size_t)N * HF * 2;
    if ((size_t)E * 4 > ubytes) ubytes = (size_t)E * 4;
    float*  P    = (float*)alloc((size_t)N * HF * 4);
    void*   Uv   = alloc(ubytes);                     // bf16 u; also sorted edges pre-gemm
    int*    colA = (int*)alloc((size_t)E * 4);
    int*    deg  = (int*)alloc((size_t)N * 4);
    float*  dinv = (float*)alloc((size_t)N * 4);
    int*    rowp = (int*)alloc((size_t)N * 4);
    int*    cnt  = (int*)alloc((size_t)M * 4);
    int*    scn  = (int*)alloc((size_t)M * 4);
    int*    sums = (int*)alloc(4096);
    float4* W4_1 = (float4*)alloc((size_t)(128 / 4) * HF * 16);
    float4* W4_2 = (float4*)alloc((size_t)(64 / 4) * HF * 16);
    float4* W4_3 = (float4*)alloc((size_t)(64 / 4) * HF * 16);
    __hip_bfloat16* U = (__hip_bfloat16*)Uv;
    u64* U64 = (u64*)Uv;
    int* es  = (int*)Uv;
    (void)ws_size; (void)n_in; (void)out_size;

    const int* src = ei;
    const int* dst = ei + E;

    // ---- build bucket-sorted edge list + CSR (scan3 folded into consumers) ----
    bhist_k<<<NBLK, 256, 0, stream>>>(dst, cnt, E, NBLK, NB);
    int nb = (M + SCAN_CHUNK - 1) / SCAN_CHUNK;
    scan1_k<<<nb, SCAN_T, 0, stream>>>(cnt, scn, sums, M);
    scan2_k<<<1, SCAN_T, 0, stream>>>(sums, nb);
    scatter_k<<<NBLK, 256, 0, stream>>>(src, dst, scn, sums, es, E, NBLK, NB);
    fill2_k<<<NB, 512, 0, stream>>>(es, scn, sums, rowp, deg, dinv, colA, E, NBLK, NB, N);

    // one-time W transforms (single launch)
    wtrans3_k<<<16, 256, 0, stream>>>(W1, W4_1, W2, W4_2, W3, W4_3);

    int gRow16 = (N + 15) / 16;   // agg: 16 nodes/block (quarter-wave per node)
    int gRow64 = (N + 63) / 64;   // gemm: 64 rows/block
    // layer 1 (K=128)
    gemm6_k<128><<<gRow64, 256, 0, stream>>>(x, W4_1, dinv, U, N);
    agg3_k<<<gRow16, 256, 0, stream>>>(U64, colA, rowp, deg, dinv, b1, P, N);
    // layer 2 (K=64)
    gemm6_k<64><<<gRow64, 256, 0, stream>>>(P, W4_2, dinv, U, N);
    agg3_k<<<gRow16, 256, 0, stream>>>(U64, colA, rowp, deg, dinv, b2, P, N);
    // layer 3 (K=64)
    gemm6_k<64><<<gRow64, 256, 0, stream>>>(P, W4_3, dinv, U, N);
    agg3_k<<<gRow16, 256, 0, stream>>>(U64, colA, rowp, deg, dinv, b3, P, N);

    pool_head_k<<<N_GRAPHS, 256, 0, stream>>>(P, batch, Wl, bl, outp, N);
}